// Round 3
// baseline (240.768 us; speedup 1.0000x reference)
//
#include <hip/hip_runtime.h>
#include <hip/hip_bf16.h>
#include <cstdint>

typedef __bf16 bf16_t;
typedef __bf16 bf16x8 __attribute__((ext_vector_type(8)));
typedef __bf16 bf16x4 __attribute__((ext_vector_type(4)));
typedef float  f32x4  __attribute__((ext_vector_type(4)));

static constexpr int Bb = 2;
static constexpr int Tt = 2048;
static constexpr int Dd = 1024;
static constexpr int Hh = 16;
static constexpr int HD = 64;

// 0.125 (1/sqrt(64)) * log2(e), folded into q at the QKV-GEMM epilogue.
#define QSCALE 0.18033688011112042f

// async global->LDS, 16B per lane. LDS dest must be wave-uniform-base + lane*16.
__device__ __forceinline__ void async_copy16(const bf16_t* gsrc, bf16_t* ldst) {
    __builtin_amdgcn_global_load_lds(
        (const __attribute__((address_space(1))) unsigned int*)gsrc,
        (__attribute__((address_space(3))) unsigned int*)ldst, 16, 0, 0);
}

// ---------------- fp32 -> bf16 elementwise (8 elems/thread) ----------------
__global__ __launch_bounds__(256) void cvt_bf16_kernel(const float* __restrict__ in,
                                                       bf16_t* __restrict__ out, int n) {
    int i = (blockIdx.x * 256 + threadIdx.x) * 8;
    if (i >= n) return;
    float4 v0 = *(const float4*)(in + i);
    float4 v1 = *(const float4*)(in + i + 4);
    bf16x8 o;
    o[0] = (bf16_t)v0.x; o[1] = (bf16_t)v0.y; o[2] = (bf16_t)v0.z; o[3] = (bf16_t)v0.w;
    o[4] = (bf16_t)v1.x; o[5] = (bf16_t)v1.y; o[6] = (bf16_t)v1.z; o[7] = (bf16_t)v1.w;
    *(bf16x8*)(out + i) = o;
}

// ------------- transpose + convert: in[R][C] fp32 -> out[C][R] bf16 -------------
__global__ __launch_bounds__(256) void transpose_cvt(const float* __restrict__ in,
                                                     bf16_t* __restrict__ out,
                                                     int R, int C) {
    __shared__ bf16_t tile[64][72];
    int tr = blockIdx.y * 64, tc = blockIdx.x * 64;
    int t = threadIdx.x;
    int r = t >> 4;
    int c4 = (t & 15) * 4;
#pragma unroll
    for (int rr = 0; rr < 4; ++rr) {
        int row = r + rr * 16;
        float4 v = *(const float4*)(in + (size_t)(tr + row) * C + tc + c4);
        tile[c4 + 0][row] = (bf16_t)v.x;
        tile[c4 + 1][row] = (bf16_t)v.y;
        tile[c4 + 2][row] = (bf16_t)v.z;
        tile[c4 + 3][row] = (bf16_t)v.w;
    }
    __syncthreads();
#pragma unroll
    for (int rr = 0; rr < 4; ++rr) {
        int oc = r + rr * 16;
        bf16x4 o;
        o[0] = tile[oc][c4 + 0];
        o[1] = tile[oc][c4 + 1];
        o[2] = tile[oc][c4 + 2];
        o[3] = tile[oc][c4 + 3];
        *(bf16x4*)(out + (size_t)(tc + oc) * R + tr + c4) = o;
    }
}

// ------------- GEMM: C[M][N] = A[M][K] * Bt[N][K]^T + bias -------------
// m97 structure: global_load_lds width-16 staging into XOR-swizzled unpadded LDS.
// LDS tile = 128 rows x 32 bf16, stored as 16B chunks; chunk at row r, slot p
// holds global k-chunk (p ^ ((r>>1)&3)) -> fragment ds_read_b128 is 2-way only.
// MODE 0: write fp32 C row-major.  MODE 1: split-scatter qkv (v packed bf16x4).
template <int MODE>
__global__ __launch_bounds__(256) void gemm_bt(
    const bf16_t* __restrict__ A, const bf16_t* __restrict__ Bt,
    const float* __restrict__ bias, float* __restrict__ Cout,
    bf16_t* __restrict__ qb_, bf16_t* __restrict__ kb_, bf16_t* __restrict__ vb_,
    int M, int N, int K) {
    __shared__ bf16_t As[128 * 32];
    __shared__ bf16_t Bs[128 * 32];
    int t = threadIdx.x;
    int wave = t >> 6, lane = t & 63;
    int l15 = lane & 15, quad = lane >> 4;
    int wm = wave & 1, wn = wave >> 1;
    int m0 = blockIdx.y * 128, n0 = blockIdx.x * 128;

    // staging map: chunk c = j*256 + t; row = c>>2, slot = c&3,
    // global sub-chunk = slot ^ ((row>>1)&3)
    int row0 = t >> 2, slot0 = t & 3;
    int sub0 = slot0 ^ ((row0 >> 1) & 3);
    int row1 = (256 + t) >> 2, slot1 = t & 3;
    int sub1 = slot1 ^ ((row1 >> 1) & 3);

    f32x4 acc[4][4];
#pragma unroll
    for (int mi = 0; mi < 4; ++mi)
#pragma unroll
        for (int ni = 0; ni < 4; ++ni) acc[mi][ni] = (f32x4){0.f, 0.f, 0.f, 0.f};

    int apos = quad ^ ((l15 >> 1) & 3);  // fragment slot (same for all mi/ni)

    for (int kk = 0; kk < K; kk += 32) {
        __syncthreads();
        async_copy16(A + (size_t)(m0 + row0) * K + kk + sub0 * 8, &As[t * 8]);
        async_copy16(A + (size_t)(m0 + row1) * K + kk + sub1 * 8, &As[2048 + t * 8]);
        async_copy16(Bt + (size_t)(n0 + row0) * K + kk + sub0 * 8, &Bs[t * 8]);
        async_copy16(Bt + (size_t)(n0 + row1) * K + kk + sub1 * 8, &Bs[2048 + t * 8]);
        __syncthreads();
        bf16x8 af[4], bf[4];
#pragma unroll
        for (int mi = 0; mi < 4; ++mi)
            af[mi] = *(const bf16x8*)(&As[(wm * 64 + mi * 16 + l15) * 32 + apos * 8]);
#pragma unroll
        for (int ni = 0; ni < 4; ++ni)
            bf[ni] = *(const bf16x8*)(&Bs[(wn * 64 + ni * 16 + l15) * 32 + apos * 8]);
#pragma unroll
        for (int mi = 0; mi < 4; ++mi)
#pragma unroll
            for (int ni = 0; ni < 4; ++ni)
                acc[mi][ni] = __builtin_amdgcn_mfma_f32_16x16x32_bf16(af[mi], bf[ni], acc[mi][ni], 0, 0, 0);
    }

    if (MODE == 1 && (n0 >> 10) == 2) {
        // v section: vb[bh][d][T]; lane's 4 acc rows are contiguous in T
#pragma unroll
        for (int ni = 0; ni < 4; ++ni) {
            int col = n0 + wn * 64 + ni * 16 + l15;
            float bv = bias[col];
            int hh = (col >> 6) & 15, dd = col & 63;
#pragma unroll
            for (int mi = 0; mi < 4; ++mi) {
                int row = m0 + wm * 64 + mi * 16 + quad * 4;
                int bb = row >> 11, tt = row & (Tt - 1);
                bf16x4 pv;
#pragma unroll
                for (int r = 0; r < 4; ++r) pv[r] = (bf16_t)(acc[mi][ni][r] + bv);
                *(bf16x4*)(vb_ + ((size_t)(bb * Hh + hh) * HD + dd) * Tt + tt) = pv;
            }
        }
        return;
    }

#pragma unroll
    for (int ni = 0; ni < 4; ++ni) {
        int col = n0 + wn * 64 + ni * 16 + l15;
        float bv = bias[col];
#pragma unroll
        for (int mi = 0; mi < 4; ++mi) {
#pragma unroll
            for (int r = 0; r < 4; ++r) {
                int row = m0 + wm * 64 + mi * 16 + quad * 4 + r;
                float v = acc[mi][ni][r] + bv;
                if (MODE == 0) {
                    Cout[(size_t)row * N + col] = v;
                } else {
                    int sec = col >> 10;
                    int hh = (col >> 6) & 15, dd = col & 63;
                    int bb = row >> 11, tt = row & (Tt - 1);
                    size_t idx = (((size_t)(bb * Hh + hh)) * Tt + tt) * HD + dd;
                    if (sec == 0) qb_[idx] = (bf16_t)(v * QSCALE);
                    else          kb_[idx] = (bf16_t)v;
                }
            }
        }
    }
}

// ------------- flash attention, causal -------------
// q/k: [BH][T][64] bf16 (q pre-scaled), v: [BH][64][T] bf16 (V^T),
// ab: [B][T][H*64] bf16. 512 thr = 8 waves; Q-tile 128; K-tile 64.
// K/V staged via global_load_lds into XOR-swizzled unpadded [64][64] tiles:
// slot p at row r holds global chunk (p ^ (r&7)) -> all LDS reads 2-way only.
__global__ __launch_bounds__(512, 4) void attn_kernel(
    const bf16_t* __restrict__ qb, const bf16_t* __restrict__ kb,
    const bf16_t* __restrict__ vb, bf16_t* __restrict__ ab) {
    __shared__ bf16_t Ks[64 * 64];
    __shared__ bf16_t Vs[64 * 64];
    __shared__ bf16_t Ps[8][16][72];
    int t = threadIdx.x;
    int wave = t >> 6, lane = t & 63;
    int l15 = lane & 15, quad = lane >> 4;
    int bh = blockIdx.y;
    int qt = 15 - (int)blockIdx.x;      // heavy blocks dispatched first
    int b = bh >> 4, h = bh & 15;
    int qbase = qt * 128 + wave * 16;
    int q = qbase + l15;
    const bf16_t* qptr = qb + (size_t)bh * Tt * HD;
    const bf16_t* kptr = kb + (size_t)bh * Tt * HD;
    const bf16_t* vptr = vb + (size_t)bh * HD * Tt;

    bf16x8 qf[2];
    qf[0] = *(const bf16x8*)(qptr + (size_t)q * HD + quad * 8);
    qf[1] = *(const bf16x8*)(qptr + (size_t)q * HD + 32 + quad * 8);

    f32x4 o[4];
#pragma unroll
    for (int g = 0; g < 4; ++g) o[g] = (f32x4){0.f, 0.f, 0.f, 0.f};
    float mrow = -1e30f, lrow = 0.f;

    // staging map: chunk t: row = t>>3, slot = t&7, global chunk = slot ^ (row&7)
    int srow = t >> 3, sslot = t & 7;
    int ssub = sslot ^ (srow & 7);
    int qmax_w = qbase + 15;
    int kx = l15 & 7;                   // krow&7 for fragment reads

    int nkt = 2 * qt + 2;
    for (int it = 0; it < nkt; ++it) {
        int kt0 = it * 64;
        __syncthreads();
        async_copy16(kptr + (size_t)(kt0 + srow) * HD + ssub * 8, &Ks[t * 8]);
        async_copy16(vptr + (size_t)srow * Tt + kt0 + ssub * 8, &Vs[t * 8]);
        __syncthreads();
        if (kt0 > qmax_w) continue;

        // S^T = K · Q^T : row = k = g*16+quad*4+r, col = q = l15
        f32x4 s[4];
#pragma unroll
        for (int g = 0; g < 4; ++g) {
            s[g] = (f32x4){0.f, 0.f, 0.f, 0.f};
            int krow = g * 16 + l15;
            bf16x8 kf0 = *(const bf16x8*)(&Ks[krow * 64 + (quad ^ kx) * 8]);
            bf16x8 kf1 = *(const bf16x8*)(&Ks[krow * 64 + ((4 + quad) ^ kx) * 8]);
            s[g] = __builtin_amdgcn_mfma_f32_16x16x32_bf16(kf0, qf[0], s[g], 0, 0, 0);
            s[g] = __builtin_amdgcn_mfma_f32_16x16x32_bf16(kf1, qf[1], s[g], 0, 0, 0);
        }

        if (kt0 + 63 > qbase) {
#pragma unroll
            for (int g = 0; g < 4; ++g)
#pragma unroll
                for (int r = 0; r < 4; ++r) {
                    int k_abs = kt0 + g * 16 + quad * 4 + r;
                    s[g][r] = (k_abs > q) ? -1e30f : s[g][r];
                }
        }

        float mloc = -1e30f;
#pragma unroll
        for (int g = 0; g < 4; ++g)
            mloc = fmaxf(mloc, fmaxf(fmaxf(s[g][0], s[g][1]), fmaxf(s[g][2], s[g][3])));
        mloc = fmaxf(mloc, __shfl_xor(mloc, 16));
        mloc = fmaxf(mloc, __shfl_xor(mloc, 32));
        float mnew = fmaxf(mrow, mloc);
        float alpha = exp2f(mrow - mnew);
        mrow = mnew;

        float rs = 0.f;
#pragma unroll
        for (int g = 0; g < 4; ++g) {
            float p0 = exp2f(s[g][0] - mnew);
            float p1 = exp2f(s[g][1] - mnew);
            float p2 = exp2f(s[g][2] - mnew);
            float p3 = exp2f(s[g][3] - mnew);
            rs += (p0 + p1) + (p2 + p3);
            bf16x4 pk;
            pk[0] = (bf16_t)p0; pk[1] = (bf16_t)p1; pk[2] = (bf16_t)p2; pk[3] = (bf16_t)p3;
            *(bf16x4*)(&Ps[wave][l15][g * 16 + quad * 4]) = pk;
        }
        rs += __shfl_xor(rs, 16);
        rs += __shfl_xor(rs, 32);
        lrow = lrow * alpha + rs;

#pragma unroll
        for (int g = 0; g < 4; ++g)
#pragma unroll
            for (int r = 0; r < 4; ++r) o[g][r] *= alpha;

        // O^T += V^T · P^T
#pragma unroll
        for (int kc = 0; kc < 2; ++kc) {
            bf16x8 pf = *(const bf16x8*)(&Ps[wave][l15][kc * 32 + quad * 8]);
#pragma unroll
            for (int g = 0; g < 4; ++g) {
                int vrow = g * 16 + l15;
                bf16x8 vf = *(const bf16x8*)(&Vs[vrow * 64 + ((kc * 4 + quad) ^ kx) * 8]);
                o[g] = __builtin_amdgcn_mfma_f32_16x16x32_bf16(vf, pf, o[g], 0, 0, 0);
            }
        }
    }

    float inv = 1.0f / lrow;
    size_t obase = ((size_t)b * Tt + q) * Dd + h * 64;
#pragma unroll
    for (int g = 0; g < 4; ++g) {
        bf16x4 ov;
#pragma unroll
        for (int r = 0; r < 4; ++r) ov[r] = (bf16_t)(o[g][r] * inv);
        *(bf16x4*)(ab + obase + g * 16 + quad * 4) = ov;
    }
}

extern "C" void kernel_launch(void* const* d_in, const int* in_sizes, int n_in,
                              void* d_out, int out_size, void* d_ws, size_t ws_size,
                              hipStream_t stream) {
    const float* x      = (const float*)d_in[0];
    const float* W_kqv  = (const float*)d_in[1];
    const float* b_kqv  = (const float*)d_in[2];
    const float* W_proj = (const float*)d_in[3];
    const float* b_proj = (const float*)d_in[4];
    float* out = (float*)d_out;
    char* ws = (char*)d_ws;
    const size_t MB = 1ull << 20;
    bf16_t* x_bf   = (bf16_t*)(ws + 0 * MB);   // 8 MB  [4096][1024]
    bf16_t* wkqvt  = (bf16_t*)(ws + 8 * MB);   // 6 MB  [3072][1024]
    bf16_t* wprojt = (bf16_t*)(ws + 14 * MB);  // 2 MB  [1024][1024]
    bf16_t* qb     = (bf16_t*)(ws + 16 * MB);  // 8 MB  [32][2048][64]  (pre-scaled)
    bf16_t* kb     = (bf16_t*)(ws + 24 * MB);  // 8 MB  [32][2048][64]
    bf16_t* vb     = (bf16_t*)(ws + 32 * MB);  // 8 MB  [32][64][2048]  (V^T)
    bf16_t* ab     = (bf16_t*)(ws + 40 * MB);  // 8 MB  [2][2048][16*64]

    cvt_bf16_kernel<<<(Bb * Tt * Dd) / (256 * 8), 256, 0, stream>>>(x, x_bf, Bb * Tt * Dd);
    transpose_cvt<<<dim3(3 * Dd / 64, Dd / 64), 256, 0, stream>>>(W_kqv, wkqvt, Dd, 3 * Dd);
    transpose_cvt<<<dim3(Dd / 64, Dd / 64), 256, 0, stream>>>(W_proj, wprojt, Dd, Dd);
    gemm_bt<1><<<dim3(3 * Dd / 128, Bb * Tt / 128), 256, 0, stream>>>(
        x_bf, wkqvt, b_kqv, nullptr, qb, kb, vb, Bb * Tt, 3 * Dd, Dd);
    attn_kernel<<<dim3(16, Bb * Hh), 512, 0, stream>>>(qb, kb, vb, ab);
    gemm_bt<0><<<dim3(Dd / 128, Bb * Tt / 128), 256, 0, stream>>>(
        ab, wprojt, b_proj, out, nullptr, nullptr, nullptr, Bb * Tt, Dd, Dd);
}

// Round 4
// 222.578 us; speedup vs baseline: 1.0817x; 1.0817x over previous
//
#include <hip/hip_runtime.h>
#include <hip/hip_bf16.h>
#include <cstdint>

typedef __bf16 bf16_t;
typedef __bf16 bf16x8 __attribute__((ext_vector_type(8)));
typedef __bf16 bf16x4 __attribute__((ext_vector_type(4)));
typedef float  f32x4  __attribute__((ext_vector_type(4)));

static constexpr int Bb = 2;
static constexpr int Tt = 2048;
static constexpr int Dd = 1024;
static constexpr int Hh = 16;
static constexpr int HD = 64;

// 0.125 (1/sqrt(64)) * log2(e), folded into q at the QKV-GEMM epilogue.
#define QSCALE 0.18033688011112042f

// async global->LDS, 16B per lane. LDS dest must be wave-uniform base + lane*16.
__device__ __forceinline__ void async_copy16(const bf16_t* gsrc, bf16_t* ldst) {
    __builtin_amdgcn_global_load_lds(
        (const __attribute__((address_space(1))) unsigned int*)gsrc,
        (__attribute__((address_space(3))) unsigned int*)ldst, 16, 0, 0);
}

// ---------------- fp32 -> bf16 elementwise (8 elems/thread) ----------------
__global__ __launch_bounds__(256) void cvt_bf16_kernel(const float* __restrict__ in,
                                                       bf16_t* __restrict__ out, int n) {
    int i = (blockIdx.x * 256 + threadIdx.x) * 8;
    if (i >= n) return;
    float4 v0 = *(const float4*)(in + i);
    float4 v1 = *(const float4*)(in + i + 4);
    bf16x8 o;
    o[0] = (bf16_t)v0.x; o[1] = (bf16_t)v0.y; o[2] = (bf16_t)v0.z; o[3] = (bf16_t)v0.w;
    o[4] = (bf16_t)v1.x; o[5] = (bf16_t)v1.y; o[6] = (bf16_t)v1.z; o[7] = (bf16_t)v1.w;
    *(bf16x8*)(out + i) = o;
}

// ------------- transpose + convert: in[R][C] fp32 -> out[C][R] bf16 -------------
__global__ __launch_bounds__(256) void transpose_cvt(const float* __restrict__ in,
                                                     bf16_t* __restrict__ out,
                                                     int R, int C) {
    __shared__ bf16_t tile[64][72];
    int tr = blockIdx.y * 64, tc = blockIdx.x * 64;
    int t = threadIdx.x;
    int r = t >> 4;
    int c4 = (t & 15) * 4;
#pragma unroll
    for (int rr = 0; rr < 4; ++rr) {
        int row = r + rr * 16;
        float4 v = *(const float4*)(in + (size_t)(tr + row) * C + tc + c4);
        tile[c4 + 0][row] = (bf16_t)v.x;
        tile[c4 + 1][row] = (bf16_t)v.y;
        tile[c4 + 2][row] = (bf16_t)v.z;
        tile[c4 + 3][row] = (bf16_t)v.w;
    }
    __syncthreads();
#pragma unroll
    for (int rr = 0; rr < 4; ++rr) {
        int oc = r + rr * 16;
        bf16x4 o;
        o[0] = tile[oc][c4 + 0];
        o[1] = tile[oc][c4 + 1];
        o[2] = tile[oc][c4 + 2];
        o[3] = tile[oc][c4 + 3];
        *(bf16x4*)(out + (size_t)(tc + oc) * R + tr + c4) = o;
    }
}

// ------------- GEMM: C[M][N] = A[M][K] * Bt[N][K]^T + bias -------------
// m97 structure, BK=64: global_load_lds width-16 into XOR-swizzled unpadded LDS
// (slot p at row r holds global chunk p^(r&7)); 16 barrier rounds at K=1024.
// MODE 0: write fp32 C row-major.  MODE 1: split-scatter qkv (v packed bf16x4).
template <int MODE>
__global__ __launch_bounds__(256) void gemm_bt(
    const bf16_t* __restrict__ A, const bf16_t* __restrict__ Bt,
    const float* __restrict__ bias, float* __restrict__ Cout,
    bf16_t* __restrict__ qb_, bf16_t* __restrict__ kb_, bf16_t* __restrict__ vb_,
    int M, int N, int K) {
    __shared__ bf16_t As[128 * 64];
    __shared__ bf16_t Bs[128 * 64];
    int t = threadIdx.x;
    int wave = t >> 6, lane = t & 63;
    int l15 = lane & 15, quad = lane >> 4;
    int wm = wave & 1, wn = wave >> 1;
    int m0 = blockIdx.y * 128, n0 = blockIdx.x * 128;

    // staging map: chunk cid = j*256 + t; row = cid>>3, slot = cid&7,
    // global sub-chunk = slot ^ (row&7)
    int rowj[4], subj[4];
#pragma unroll
    for (int j = 0; j < 4; ++j) {
        int cid = j * 256 + t;
        rowj[j] = cid >> 3;
        subj[j] = (cid & 7) ^ (rowj[j] & 7);
    }

    f32x4 acc[4][4];
#pragma unroll
    for (int mi = 0; mi < 4; ++mi)
#pragma unroll
        for (int ni = 0; ni < 4; ++ni) acc[mi][ni] = (f32x4){0.f, 0.f, 0.f, 0.f};

    int kx = l15 & 7;  // fragment-row swizzle key

    for (int kk = 0; kk < K; kk += 64) {
        __syncthreads();
#pragma unroll
        for (int j = 0; j < 4; ++j) {
            async_copy16(A + (size_t)(m0 + rowj[j]) * K + kk + subj[j] * 8,
                         &As[(j * 256 + t) * 8]);
            async_copy16(Bt + (size_t)(n0 + rowj[j]) * K + kk + subj[j] * 8,
                         &Bs[(j * 256 + t) * 8]);
        }
        __syncthreads();
#pragma unroll
        for (int kb = 0; kb < 2; ++kb) {
            bf16x8 af[4], bf[4];
#pragma unroll
            for (int mi = 0; mi < 4; ++mi) {
                int r = wm * 64 + mi * 16 + l15;
                af[mi] = *(const bf16x8*)(&As[r * 64 + ((kb * 4 + quad) ^ kx) * 8]);
            }
#pragma unroll
            for (int ni = 0; ni < 4; ++ni) {
                int r = wn * 64 + ni * 16 + l15;
                bf[ni] = *(const bf16x8*)(&Bs[r * 64 + ((kb * 4 + quad) ^ kx) * 8]);
            }
#pragma unroll
            for (int mi = 0; mi < 4; ++mi)
#pragma unroll
                for (int ni = 0; ni < 4; ++ni)
                    acc[mi][ni] = __builtin_amdgcn_mfma_f32_16x16x32_bf16(af[mi], bf[ni], acc[mi][ni], 0, 0, 0);
        }
    }

    if (MODE == 1 && (n0 >> 10) == 2) {
        // v section: vb[bh][d][T]; lane's 4 acc rows contiguous in T
#pragma unroll
        for (int ni = 0; ni < 4; ++ni) {
            int col = n0 + wn * 64 + ni * 16 + l15;
            float bv = bias[col];
            int hh = (col >> 6) & 15, dd = col & 63;
#pragma unroll
            for (int mi = 0; mi < 4; ++mi) {
                int row = m0 + wm * 64 + mi * 16 + quad * 4;
                int bb = row >> 11, tt = row & (Tt - 1);
                bf16x4 pv;
#pragma unroll
                for (int r = 0; r < 4; ++r) pv[r] = (bf16_t)(acc[mi][ni][r] + bv);
                *(bf16x4*)(vb_ + ((size_t)(bb * Hh + hh) * HD + dd) * Tt + tt) = pv;
            }
        }
        return;
    }

#pragma unroll
    for (int ni = 0; ni < 4; ++ni) {
        int col = n0 + wn * 64 + ni * 16 + l15;
        float bv = bias[col];
#pragma unroll
        for (int mi = 0; mi < 4; ++mi) {
#pragma unroll
            for (int r = 0; r < 4; ++r) {
                int row = m0 + wm * 64 + mi * 16 + quad * 4 + r;
                float v = acc[mi][ni][r] + bv;
                if (MODE == 0) {
                    Cout[(size_t)row * N + col] = v;
                } else {
                    int sec = col >> 10;
                    int hh = (col >> 6) & 15, dd = col & 63;
                    int bb = row >> 11, tt = row & (Tt - 1);
                    size_t idx = (((size_t)(bb * Hh + hh)) * Tt + tt) * HD + dd;
                    if (sec == 0) qb_[idx] = (bf16_t)(v * QSCALE);
                    else          kb_[idx] = (bf16_t)v;
                }
            }
        }
    }
}

// ------------- flash attention, causal -------------
// q/k: [BH][T][64] bf16 (q pre-scaled), v: [BH][64][T] bf16 (V^T),
// ab: [B][T][H*64] bf16. 512 thr = 8 waves; Q-tile 128; K processed in
// PAIRS of 64 (128 k per barrier round -> heavy block 16 rounds, not 32).
// Staging: VGPR loads + ds_write (padded LDS, round-2 proven) with explicit
// next-round prefetch into registers issued right after the LDS-ready barrier.
__global__ __launch_bounds__(512, 3) void attn_kernel(
    const bf16_t* __restrict__ qb, const bf16_t* __restrict__ kb,
    const bf16_t* __restrict__ vb, bf16_t* __restrict__ ab) {
    __shared__ bf16_t Ks[128][72];      // [k-pair row][d]
    __shared__ bf16_t Vs[64][136];      // [d][k-pair col] (V^T)
    __shared__ bf16_t Ps[8][16][72];    // per-wave [q][k(64)]
    int t = threadIdx.x;
    int wave = t >> 6, lane = t & 63;
    int l15 = lane & 15, quad = lane >> 4;
    int bh = blockIdx.y;
    int x = blockIdx.x;
    int qt = (bh & 1) ? x : (15 - x);   // pair heavy+light across bh
    int b = bh >> 4, h = bh & 15;
    int qbase = qt * 128 + wave * 16;
    int q = qbase + l15;
    const bf16_t* qptr = qb + (size_t)bh * Tt * HD;
    const bf16_t* kptr = kb + (size_t)bh * Tt * HD;
    const bf16_t* vptr = vb + (size_t)bh * HD * Tt;

    bf16x8 qf[2];
    qf[0] = *(const bf16x8*)(qptr + (size_t)q * HD + quad * 8);
    qf[1] = *(const bf16x8*)(qptr + (size_t)q * HD + 32 + quad * 8);

    f32x4 o[4];
#pragma unroll
    for (int g = 0; g < 4; ++g) o[g] = (f32x4){0.f, 0.f, 0.f, 0.f};
    float mrow = -1e30f, lrow = 0.f;

    // staging indices: K pair tile 128 rows x 64 d; V pair tile 64 d x 128 k
    int ksr = t >> 2;           // 0..127
    int ksc = (t & 3) * 16;     // 0,16,32,48
    int vdr = t >> 3;           // 0..63
    int vkc = (t & 7) * 16;     // 0..112
    int qmax_w = qbase + 15;

    int nR = qt + 1;
    bf16x8 kr0, kr1, vr0, vr1;
    {
        const bf16_t* kg = kptr + (size_t)ksr * HD + ksc;
        kr0 = *(const bf16x8*)(kg);
        kr1 = *(const bf16x8*)(kg + 8);
        const bf16_t* vg = vptr + (size_t)vdr * Tt + vkc;
        vr0 = *(const bf16x8*)(vg);
        vr1 = *(const bf16x8*)(vg + 8);
    }

    for (int it = 0; it < nR; ++it) {
        if (it) __syncthreads();
        *(bf16x8*)(&Ks[ksr][ksc])     = kr0;
        *(bf16x8*)(&Ks[ksr][ksc + 8]) = kr1;
        *(bf16x8*)(&Vs[vdr][vkc])     = vr0;
        *(bf16x8*)(&Vs[vdr][vkc + 8]) = vr1;
        __syncthreads();
        if (it + 1 < nR) {  // prefetch next round; latency overlaps compute
            int kt = (it + 1) * 128;
            const bf16_t* kg = kptr + (size_t)(kt + ksr) * HD + ksc;
            kr0 = *(const bf16x8*)(kg);
            kr1 = *(const bf16x8*)(kg + 8);
            const bf16_t* vg = vptr + (size_t)vdr * Tt + kt + vkc;
            vr0 = *(const bf16x8*)(vg);
            vr1 = *(const bf16x8*)(vg + 8);
        }

#pragma unroll
        for (int sub = 0; sub < 2; ++sub) {
            int kt0 = it * 128 + sub * 64;
            if (kt0 > qmax_w) continue;  // wave-uniform: past diagonal

            // S^T = K · Q^T : row = k = g*16+quad*4+r, col = q = l15
            f32x4 s[4];
#pragma unroll
            for (int g = 0; g < 4; ++g) {
                s[g] = (f32x4){0.f, 0.f, 0.f, 0.f};
                int krow = sub * 64 + g * 16 + l15;
                bf16x8 kf0 = *(const bf16x8*)(&Ks[krow][quad * 8]);
                bf16x8 kf1 = *(const bf16x8*)(&Ks[krow][32 + quad * 8]);
                s[g] = __builtin_amdgcn_mfma_f32_16x16x32_bf16(kf0, qf[0], s[g], 0, 0, 0);
                s[g] = __builtin_amdgcn_mfma_f32_16x16x32_bf16(kf1, qf[1], s[g], 0, 0, 0);
            }

            if (kt0 + 63 > qbase) {  // diagonal sub-tile: mask
#pragma unroll
                for (int g = 0; g < 4; ++g)
#pragma unroll
                    for (int r = 0; r < 4; ++r) {
                        int k_abs = kt0 + g * 16 + quad * 4 + r;
                        s[g][r] = (k_abs > q) ? -1e30f : s[g][r];
                    }
            }

            float mloc = -1e30f;
#pragma unroll
            for (int g = 0; g < 4; ++g)
                mloc = fmaxf(mloc, fmaxf(fmaxf(s[g][0], s[g][1]), fmaxf(s[g][2], s[g][3])));
            mloc = fmaxf(mloc, __shfl_xor(mloc, 16));
            mloc = fmaxf(mloc, __shfl_xor(mloc, 32));
            float mnew = fmaxf(mrow, mloc);
            float alpha = exp2f(mrow - mnew);
            mrow = mnew;

            float rs = 0.f;
#pragma unroll
            for (int g = 0; g < 4; ++g) {
                float p0 = exp2f(s[g][0] - mnew);
                float p1 = exp2f(s[g][1] - mnew);
                float p2 = exp2f(s[g][2] - mnew);
                float p3 = exp2f(s[g][3] - mnew);
                rs += (p0 + p1) + (p2 + p3);
                bf16x4 pk;
                pk[0] = (bf16_t)p0; pk[1] = (bf16_t)p1; pk[2] = (bf16_t)p2; pk[3] = (bf16_t)p3;
                *(bf16x4*)(&Ps[wave][l15][g * 16 + quad * 4]) = pk;
            }
            rs += __shfl_xor(rs, 16);
            rs += __shfl_xor(rs, 32);
            lrow = lrow * alpha + rs;

#pragma unroll
            for (int g = 0; g < 4; ++g)
#pragma unroll
                for (int r = 0; r < 4; ++r) o[g][r] *= alpha;

            // O^T += V^T · P^T
#pragma unroll
            for (int kc = 0; kc < 2; ++kc) {
                bf16x8 pf = *(const bf16x8*)(&Ps[wave][l15][kc * 32 + quad * 8]);
#pragma unroll
                for (int g = 0; g < 4; ++g) {
                    bf16x8 vf = *(const bf16x8*)(&Vs[g * 16 + l15][sub * 64 + kc * 32 + quad * 8]);
                    o[g] = __builtin_amdgcn_mfma_f32_16x16x32_bf16(vf, pf, o[g], 0, 0, 0);
                }
            }
        }
    }

    float inv = 1.0f / lrow;
    size_t obase = ((size_t)b * Tt + q) * Dd + h * 64;
#pragma unroll
    for (int g = 0; g < 4; ++g) {
        bf16x4 ov;
#pragma unroll
        for (int r = 0; r < 4; ++r) ov[r] = (bf16_t)(o[g][r] * inv);
        *(bf16x4*)(ab + obase + g * 16 + quad * 4) = ov;
    }
}

extern "C" void kernel_launch(void* const* d_in, const int* in_sizes, int n_in,
                              void* d_out, int out_size, void* d_ws, size_t ws_size,
                              hipStream_t stream) {
    const float* x      = (const float*)d_in[0];
    const float* W_kqv  = (const float*)d_in[1];
    const float* b_kqv  = (const float*)d_in[2];
    const float* W_proj = (const float*)d_in[3];
    const float* b_proj = (const float*)d_in[4];
    float* out = (float*)d_out;
    char* ws = (char*)d_ws;
    const size_t MB = 1ull << 20;
    bf16_t* x_bf   = (bf16_t*)(ws + 0 * MB);   // 8 MB  [4096][1024]
    bf16_t* wkqvt  = (bf16_t*)(ws + 8 * MB);   // 6 MB  [3072][1024]
    bf16_t* wprojt = (bf16_t*)(ws + 14 * MB);  // 2 MB  [1024][1024]
    bf16_t* qb     = (bf16_t*)(ws + 16 * MB);  // 8 MB  [32][2048][64]  (pre-scaled)
    bf16_t* kb     = (bf16_t*)(ws + 24 * MB);  // 8 MB  [32][2048][64]
    bf16_t* vb     = (bf16_t*)(ws + 32 * MB);  // 8 MB  [32][64][2048]  (V^T)
    bf16_t* ab     = (bf16_t*)(ws + 40 * MB);  // 8 MB  [2][2048][16*64]

    cvt_bf16_kernel<<<(Bb * Tt * Dd) / (256 * 8), 256, 0, stream>>>(x, x_bf, Bb * Tt * Dd);
    transpose_cvt<<<dim3(3 * Dd / 64, Dd / 64), 256, 0, stream>>>(W_kqv, wkqvt, Dd, 3 * Dd);
    transpose_cvt<<<dim3(Dd / 64, Dd / 64), 256, 0, stream>>>(W_proj, wprojt, Dd, Dd);
    gemm_bt<1><<<dim3(3 * Dd / 128, Bb * Tt / 128), 256, 0, stream>>>(
        x_bf, wkqvt, b_kqv, nullptr, qb, kb, vb, Bb * Tt, 3 * Dd, Dd);
    attn_kernel<<<dim3(16, Bb * Hh), 512, 0, stream>>>(qb, kb, vb, ab);
    gemm_bt<0><<<dim3(Dd / 128, Bb * Tt / 128), 256, 0, stream>>>(
        ab, wprojt, b_proj, out, nullptr, nullptr, nullptr, Bb * Tt, Dd, Dd);
}